// Round 1
// baseline (133.755 us; speedup 1.0000x reference)
//
#include <hip/hip_runtime.h>
#include <math.h>

// SWALP global block-quantize:
//   m = max|x|; e = clamp(floor(log2 m), -128, 127)
//   scale = 2^(-e+6); i = clamp(rne(x*scale), -128, 127); out = i * 2^(e-6)
//   (out = x unchanged if m == 0)

__global__ void bq_init_ws(unsigned int* ws) {
    if (threadIdx.x == 0 && blockIdx.x == 0) ws[0] = 0u;
}

__global__ __launch_bounds__(256) void bq_absmax(const float* __restrict__ x,
                                                 unsigned int* __restrict__ ws,
                                                 int n) {
    const int n4 = n >> 2;
    const float4* __restrict__ x4 = (const float4*)x;
    int tid = blockIdx.x * blockDim.x + threadIdx.x;
    int stride = gridDim.x * blockDim.x;
    float m = 0.0f;
    for (int i = tid; i < n4; i += stride) {
        float4 v = x4[i];
        m = fmaxf(m, fmaxf(fmaxf(fabsf(v.x), fabsf(v.y)),
                           fmaxf(fabsf(v.z), fabsf(v.w))));
    }
    // scalar tail (n is divisible by 4 here, but stay general)
    for (int i = (n4 << 2) + tid; i < n; i += stride) m = fmaxf(m, fabsf(x[i]));

    // wave-64 butterfly reduce
    #pragma unroll
    for (int off = 32; off > 0; off >>= 1)
        m = fmaxf(m, __shfl_xor(m, off, 64));

    __shared__ float sm[4];  // 256 threads = 4 waves
    int wid = threadIdx.x >> 6;
    if ((threadIdx.x & 63) == 0) sm[wid] = m;
    __syncthreads();
    if (threadIdx.x == 0) {
        float bm = fmaxf(fmaxf(sm[0], sm[1]), fmaxf(sm[2], sm[3]));
        // |x| >= 0 so uint bit-pattern order == float order; device-scope atomic
        atomicMax(ws, __float_as_uint(bm));
    }
}

__global__ __launch_bounds__(256) void bq_quant(const float* __restrict__ x,
                                                float* __restrict__ out,
                                                const unsigned int* __restrict__ ws,
                                                int n) {
    const float maxe = __uint_as_float(ws[0]);
    const int n4 = n >> 2;
    const float4* __restrict__ x4 = (const float4*)x;
    float4* __restrict__ o4 = (float4*)out;
    int tid = blockIdx.x * blockDim.x + threadIdx.x;
    int stride = gridDim.x * blockDim.x;

    if (maxe == 0.0f) {  // reference returns data unchanged
        for (int i = tid; i < n4; i += stride) o4[i] = x4[i];
        for (int i = (n4 << 2) + tid; i < n; i += stride) out[i] = x[i];
        return;
    }

    // floor(log2(maxe)) exactly (ilogbf handles subnormals too), then clamp
    int e = ilogbf(maxe);
    e = max(-128, min(127, e));
    const float scale    = ldexpf(1.0f, -e + 6);  // 2^(-e + (bits-2)), exact
    const float invscale = ldexpf(1.0f, e - 6);   // 2^(e - (bits-2)), exact

    for (int i = tid; i < n4; i += stride) {
        float4 v = x4[i];
        float4 r;
        float a = rintf(v.x * scale);  // RNE, matches jnp.round
        float b = rintf(v.y * scale);
        float c = rintf(v.z * scale);
        float d = rintf(v.w * scale);
        a = fminf(fmaxf(a, -128.0f), 127.0f);
        b = fminf(fmaxf(b, -128.0f), 127.0f);
        c = fminf(fmaxf(c, -128.0f), 127.0f);
        d = fminf(fmaxf(d, -128.0f), 127.0f);
        r.x = a * invscale;
        r.y = b * invscale;
        r.z = c * invscale;
        r.w = d * invscale;
        o4[i] = r;
    }
    for (int i = (n4 << 2) + tid; i < n; i += stride) {
        float a = rintf(x[i] * scale);
        a = fminf(fmaxf(a, -128.0f), 127.0f);
        out[i] = a * invscale;
    }
}

extern "C" void kernel_launch(void* const* d_in, const int* in_sizes, int n_in,
                              void* d_out, int out_size, void* d_ws, size_t ws_size,
                              hipStream_t stream) {
    const float* x = (const float*)d_in[0];
    float* out = (float*)d_out;
    unsigned int* ws = (unsigned int*)d_ws;
    int n = in_sizes[0];

    const int block = 256;
    const int grid = 2048;  // ~8 blocks/CU, grid-stride covers the rest

    hipLaunchKernelGGL(bq_init_ws, dim3(1), dim3(64), 0, stream, ws);
    hipLaunchKernelGGL(bq_absmax, dim3(grid), dim3(block), 0, stream, x, ws, n);
    hipLaunchKernelGGL(bq_quant, dim3(grid), dim3(block), 0, stream, x, out, ws, n);
}

// Round 3
// 94.874 us; speedup vs baseline: 1.4098x; 1.4098x over previous
//
#include <hip/hip_runtime.h>
#include <math.h>

// SWALP global block-quantize, 2-kernel plan:
//   k1: per-block absmax -> partial[blockIdx] (unconditional write, no init needed)
//   k2: every block redundantly reduces the 2048 partials (L2-cheap), then
//       quantizes with nontemporal stores (keep input L3-resident for the re-read)

#define GRID1 2048  // 8 blocks/CU at 256 threads; partials = 8 KB in d_ws

typedef float v4f __attribute__((ext_vector_type(4)));  // clang vector: ok for nontemporal builtins

__global__ __launch_bounds__(256) void bq_absmax(const float* __restrict__ x,
                                                 float* __restrict__ partial,
                                                 int n) {
    const int n4 = n >> 2;
    const v4f* __restrict__ x4 = (const v4f*)x;
    int tid = blockIdx.x * blockDim.x + threadIdx.x;
    int stride = gridDim.x * blockDim.x;
    float m = 0.0f;
    for (int i = tid; i < n4; i += stride) {
        v4f v = x4[i];
        m = fmaxf(fmaxf(fabsf(v.x), fabsf(v.y)),
                  fmaxf(fmaxf(fabsf(v.z), fabsf(v.w)), m));
    }
    for (int i = (n4 << 2) + tid; i < n; i += stride) m = fmaxf(m, fabsf(x[i]));

    #pragma unroll
    for (int off = 32; off > 0; off >>= 1)
        m = fmaxf(m, __shfl_xor(m, off, 64));

    __shared__ float sm[4];
    if ((threadIdx.x & 63) == 0) sm[threadIdx.x >> 6] = m;
    __syncthreads();
    if (threadIdx.x == 0)
        partial[blockIdx.x] = fmaxf(fmaxf(sm[0], sm[1]), fmaxf(sm[2], sm[3]));
}

__global__ __launch_bounds__(256) void bq_quant(const float* __restrict__ x,
                                                float* __restrict__ out,
                                                const float* __restrict__ partial,
                                                int n) {
    // Redundant per-block reduce of the GRID1 partials (8 KB, L2-resident).
    float bm = 0.0f;
    #pragma unroll
    for (int k = 0; k < GRID1 / 256; ++k)
        bm = fmaxf(bm, partial[threadIdx.x + k * 256]);
    #pragma unroll
    for (int off = 32; off > 0; off >>= 1)
        bm = fmaxf(bm, __shfl_xor(bm, off, 64));
    __shared__ float sm[4];
    if ((threadIdx.x & 63) == 0) sm[threadIdx.x >> 6] = bm;
    __syncthreads();
    const float maxe = fmaxf(fmaxf(sm[0], sm[1]), fmaxf(sm[2], sm[3]));

    const int n4 = n >> 2;
    const v4f* __restrict__ x4 = (const v4f*)x;
    v4f* __restrict__ o4 = (v4f*)out;
    int tid = blockIdx.x * blockDim.x + threadIdx.x;
    int stride = gridDim.x * blockDim.x;

    if (maxe == 0.0f) {  // reference returns data unchanged
        for (int i = tid; i < n4; i += stride)
            __builtin_nontemporal_store(x4[i], &o4[i]);
        for (int i = (n4 << 2) + tid; i < n; i += stride) out[i] = x[i];
        return;
    }

    // floor(log2(maxe)) exactly, clamp to signed-8 exponent range
    int e = ilogbf(maxe);
    e = max(-128, min(127, e));
    const float scale    = ldexpf(1.0f, -e + 6);  // 2^(-e + (bits-2)), exact
    const float invscale = ldexpf(1.0f, e - 6);   // 2^(e - (bits-2)), exact

    for (int i = tid; i < n4; i += stride) {
        v4f v = x4[i];
        float a = rintf(v.x * scale);  // RNE == jnp.round
        float b = rintf(v.y * scale);
        float c = rintf(v.z * scale);
        float d = rintf(v.w * scale);
        a = fminf(fmaxf(a, -128.0f), 127.0f);
        b = fminf(fmaxf(b, -128.0f), 127.0f);
        c = fminf(fmaxf(c, -128.0f), 127.0f);
        d = fminf(fmaxf(d, -128.0f), 127.0f);
        v4f r;
        r.x = a * invscale;
        r.y = b * invscale;
        r.z = c * invscale;
        r.w = d * invscale;
        // nontemporal: stream the output past L3 so the input stays resident
        __builtin_nontemporal_store(r, &o4[i]);
    }
    for (int i = (n4 << 2) + tid; i < n; i += stride) {
        float a = rintf(x[i] * scale);
        a = fminf(fmaxf(a, -128.0f), 127.0f);
        out[i] = a * invscale;
    }
}

extern "C" void kernel_launch(void* const* d_in, const int* in_sizes, int n_in,
                              void* d_out, int out_size, void* d_ws, size_t ws_size,
                              hipStream_t stream) {
    const float* x = (const float*)d_in[0];
    float* out = (float*)d_out;
    float* partial = (float*)d_ws;  // GRID1 floats = 8 KB
    int n = in_sizes[0];

    const int block = 256;

    hipLaunchKernelGGL(bq_absmax, dim3(GRID1), dim3(block), 0, stream, x, partial, n);
    hipLaunchKernelGGL(bq_quant,  dim3(GRID1), dim3(block), 0, stream, x, out, partial, n);
}

// Round 4
// 90.499 us; speedup vs baseline: 1.4780x; 1.0483x over previous
//
#include <hip/hip_runtime.h>
#include <math.h>

// SWALP global block-quantize, 2-kernel plan:
//   k1: per-block absmax -> partial[blockIdx] (ascending order, loads populate L3)
//   k2: redundant partial-reduce, then quantize traversing in REVERSE chunk order
//       (L3-recency-friendly) with system-scope nontemporal stores (sc0 sc1 nt)
//       so the 205 MB output stream doesn't evict the L3-resident input.

#define GRID1 2048  // 8 blocks/CU at 256 threads; partials = 8 KB in d_ws

typedef float v4f __attribute__((ext_vector_type(4)));

__device__ inline void store_stream(v4f* p, v4f v) {
    // system-scope + non-temporal: bypass/no-allocate in L1/L2/MALL
    asm volatile("global_store_dwordx4 %0, %1, off sc0 sc1 nt" :: "v"(p), "v"(v));
}

__global__ __launch_bounds__(256) void bq_absmax(const float* __restrict__ x,
                                                 float* __restrict__ partial,
                                                 int n) {
    const int n4 = n >> 2;
    const v4f* __restrict__ x4 = (const v4f*)x;
    int tid = blockIdx.x * blockDim.x + threadIdx.x;
    int stride = gridDim.x * blockDim.x;
    float m = 0.0f;
    for (int i = tid; i < n4; i += stride) {
        v4f v = x4[i];
        m = fmaxf(fmaxf(fabsf(v.x), fabsf(v.y)),
                  fmaxf(fmaxf(fabsf(v.z), fabsf(v.w)), m));
    }
    for (int i = (n4 << 2) + tid; i < n; i += stride) m = fmaxf(m, fabsf(x[i]));

    #pragma unroll
    for (int off = 32; off > 0; off >>= 1)
        m = fmaxf(m, __shfl_xor(m, off, 64));

    __shared__ float sm[4];
    if ((threadIdx.x & 63) == 0) sm[threadIdx.x >> 6] = m;
    __syncthreads();
    if (threadIdx.x == 0)
        partial[blockIdx.x] = fmaxf(fmaxf(sm[0], sm[1]), fmaxf(sm[2], sm[3]));
}

__global__ __launch_bounds__(256) void bq_quant(const float* __restrict__ x,
                                                float* __restrict__ out,
                                                const float* __restrict__ partial,
                                                int n) {
    // Redundant per-block reduce of the GRID1 partials (8 KB, L2-resident).
    float bm = 0.0f;
    #pragma unroll
    for (int k = 0; k < GRID1 / 256; ++k)
        bm = fmaxf(bm, partial[threadIdx.x + k * 256]);
    #pragma unroll
    for (int off = 32; off > 0; off >>= 1)
        bm = fmaxf(bm, __shfl_xor(bm, off, 64));
    __shared__ float sm[4];
    if ((threadIdx.x & 63) == 0) sm[threadIdx.x >> 6] = bm;
    __syncthreads();
    const float maxe = fmaxf(fmaxf(sm[0], sm[1]), fmaxf(sm[2], sm[3]));

    const int n4 = n >> 2;
    const v4f* __restrict__ x4 = (const v4f*)x;
    v4f* __restrict__ o4 = (v4f*)out;
    const int tid = blockIdx.x * blockDim.x + threadIdx.x;
    const int T = gridDim.x * blockDim.x;
    const int C = (n4 + T - 1) / T;  // chunk count

    if (maxe == 0.0f) {  // reference returns data unchanged
        for (int c = C - 1; c >= 0; --c) {
            int i = c * T + tid;
            if (i < n4) store_stream(&o4[i], x4[i]);
        }
        for (int i = (n4 << 2) + tid; i < n; i += T) out[i] = x[i];
        return;
    }

    // floor(log2(maxe)) exactly, clamp to signed-8 exponent range
    int e = ilogbf(maxe);
    e = max(-128, min(127, e));
    const float scale    = ldexpf(1.0f, -e + 6);  // 2^(-e + (bits-2)), exact
    const float invscale = ldexpf(1.0f, e - 6);   // 2^(e - (bits-2)), exact

    // REVERSE chunk order: read most-recently-cached (tail) data first so the
    // write stream's MALL evictions (oldest = low addresses) trail the reads.
    for (int c = C - 1; c >= 0; --c) {
        int i = c * T + tid;
        if (i < n4) {
            v4f v = x4[i];
            float a = rintf(v.x * scale);  // RNE == jnp.round
            float b = rintf(v.y * scale);
            float cc = rintf(v.z * scale);
            float d = rintf(v.w * scale);
            a  = fminf(fmaxf(a,  -128.0f), 127.0f);
            b  = fminf(fmaxf(b,  -128.0f), 127.0f);
            cc = fminf(fmaxf(cc, -128.0f), 127.0f);
            d  = fminf(fmaxf(d,  -128.0f), 127.0f);
            v4f r;
            r.x = a * invscale;
            r.y = b * invscale;
            r.z = cc * invscale;
            r.w = d * invscale;
            store_stream(&o4[i], r);
        }
    }
    for (int i = (n4 << 2) + tid; i < n; i += T) {
        float a = rintf(x[i] * scale);
        a = fminf(fmaxf(a, -128.0f), 127.0f);
        out[i] = a * invscale;
    }
}

extern "C" void kernel_launch(void* const* d_in, const int* in_sizes, int n_in,
                              void* d_out, int out_size, void* d_ws, size_t ws_size,
                              hipStream_t stream) {
    const float* x = (const float*)d_in[0];
    float* out = (float*)d_out;
    float* partial = (float*)d_ws;  // GRID1 floats = 8 KB
    int n = in_sizes[0];

    const int block = 256;

    hipLaunchKernelGGL(bq_absmax, dim3(GRID1), dim3(block), 0, stream, x, partial, n);
    hipLaunchKernelGGL(bq_quant,  dim3(GRID1), dim3(block), 0, stream, x, out, partial, n);
}